// Round 8
// baseline (1387.514 us; speedup 1.0000x reference)
//
#include <hip/hip_runtime.h>
#include <stdint.h>

#define B_ 32
#define P_ 8732
#define C_ 21
#define TOPK 200
#define TGT 228        // count-search acceptance window center [200,256]
#define TGT0 300       // scatter pre-filter target count (mean; sigma~17)
#define SUBCAP 28      // per-(task,chunk) slot capacity; Poisson(8.8) P(>28)~1e-7
#define NCH2 35        // ceil(P_/256) chunks
#define NSLOT (NCH2 * SUBCAP)   // 980 slots/task
#define CONF_T 0.01f
#define NMS_T 0.45f
#define NT 512         // 8-wave blocks
#define KV4 5          // slow-path strided load: ceil((P_/4)/NT)
#define NTASK (B_ * C_)
#define SPIN_SCALE 10
#define SPIN_CAP 50000ull      // ticks; >> any sane 10x phase time, << ms even @25MHz

__device__ __forceinline__ uint32_t f2s(float f) {
    uint32_t u = __float_as_uint(f);
    return (u & 0x80000000u) ? ~u : (u | 0x80000000u);
}
__device__ __forceinline__ float s2f(uint32_t s) {
    uint32_t b = (s & 0x80000000u) ? (s & 0x7FFFFFFFu) : ~s;
    return __uint_as_float(b);
}
__device__ __forceinline__ uint32_t keyof(float v) {
    return f2s((v > CONF_T) ? v : -1.0f);
}
__device__ __forceinline__ uint32_t thr0() {
    return f2s(1.0f - (float)TGT0 / (float)P_);   // folds to a constant
}

// conf (B,P,C) -> chunked per-task candidate lists, NO atomics anywhere.
__global__ __launch_bounds__(256) void scatter_cands(const float* __restrict__ conf,
                                                     uint32_t* __restrict__ gccnt,
                                                     uint64_t* __restrict__ gcand) {
    const int b = blockIdx.x / NCH2;
    const int ch = blockIdx.x % NCH2;
    const int p0 = ch * 256;
    const int n = min(256, P_ - p0);          // 256 or 28
    const int tid = threadIdx.x;
    const int lane = tid & 63;
    const int cs = tid >> 6;                  // wave id = class slice 0..3
    __shared__ float tile[256 * C_];
    const float4* src4 = (const float4*)(conf + ((size_t)b * P_ + p0) * C_);
    float4* tile4 = (float4*)tile;
    const int tot4 = (n * C_) >> 2;
    for (int i = tid; i < tot4; i += 256) tile4[i] = src4[i];
    __syncthreads();
    const uint32_t T0 = thr0();
    for (int c = (cs == 0 ? 4 : cs); c < C_; c += 4) {   // class 0 output is zeroed: skip
        uint32_t kk[4];
        #pragma unroll
        for (int k = 0; k < 4; ++k) {
            const int r = lane + 64 * k;
            if (r < n) kk[k] = keyof(tile[r * C_ + c]);
            else       kk[k] = 0u;            // 0 < T0 (T0 has top bit set)
        }
        const unsigned long long m0 = __ballot(kk[0] >= T0);
        const unsigned long long m1 = __ballot(kk[1] >= T0);
        const unsigned long long m2 = __ballot(kk[2] >= T0);
        const unsigned long long m3 = __ballot(kk[3] >= T0);
        const int c0 = __popcll(m0), c1 = __popcll(m1), c2 = __popcll(m2), c3 = __popcll(m3);
        const int total = c0 + c1 + c2 + c3;
        const int task = b * C_ + c;
        uint64_t* dst = gcand + ((size_t)task * NCH2 + ch) * SUBCAP;
        {
            const unsigned long long below = (1ull << lane) - 1ull;
            const int cum[4] = {0, c0, c0 + c1, c0 + c1 + c2};
            const unsigned long long mm[4] = {m0, m1, m2, m3};
            #pragma unroll
            for (int k = 0; k < 4; ++k) {
                if (kk[k] >= T0) {
                    const int pos = cum[k] + __popcll(mm[k] & below);
                    if (pos < SUBCAP) {
                        const int p = p0 + lane + 64 * k;
                        dst[pos] = ((uint64_t)kk[k] << 32) | (uint32_t)(~(uint32_t)p);
                    }
                }
            }
        }
        if (lane == 0) gccnt[(size_t)task * NCH2 + ch] = (uint32_t)total;
    }
}

// Production detect: exact Round-3 kernel (best measured: 48.1us, e2e 122.6)
// + tid0 s_memrealtime stamps at phase boundaries -> tstamp (diagnostic only).
template<bool HASWS>
__global__ __launch_bounds__(NT, 6) void detect_kernel(
    const float* __restrict__ loc, const float* __restrict__ prior,
    const uint32_t* __restrict__ gccnt, const uint64_t* __restrict__ gcand,
    const float* __restrict__ conf, float* __restrict__ out,
    unsigned long long* __restrict__ tstamp)
{
    const int task = blockIdx.x;
    const int b = task / C_;
    const int c = task % C_;
    const int tid = threadIdx.x;
    const int lane = tid & 63;
    float* outp = out + (size_t)task * TOPK * 5;

    if (c == 0) {  // out.at[:,0].set(0.0)
        for (int e = tid; e < TOPK * 5; e += NT) outp[e] = 0.0f;
        return;
    }

    const bool dT = (tstamp != nullptr) && (tid == 0);
    unsigned long long ts[9];
    if (dT) ts[0] = __builtin_amdgcn_s_memrealtime();

    __shared__ uint64_t cand[256];
    __shared__ float4 bbox[TOPK];
    __shared__ float bs[TOPK];
    __shared__ float sar[TOPK];
    __shared__ unsigned long long msk[TOPK * 4];
    __shared__ unsigned long long vmask[4];
    __shared__ int order[TOPK];
    __shared__ int s_cnt, s_nk;
    __shared__ int s_c2[2];
    __shared__ int s_c3[3];            // 3-slot rotation: 1 barrier/search-iter
    __shared__ uint32_t s_ccnt[NCH2];
    __shared__ int s_gc, s_bad;

    const uint32_t T0 = thr0();

    if (tid == 0) s_cnt = 0;
    if (tid < 2) s_c2[tid] = 0;
    if (tid < 3) s_c3[tid] = 0;
    if (HASWS && tid < NCH2) s_ccnt[tid] = gccnt[(size_t)task * NCH2 + tid];
    for (int i2 = tid; i2 < TOPK * 4; i2 += NT) msk[i2] = 0ull;
    __syncthreads();
    if (dT) ts[1] = __builtin_amdgcn_s_memrealtime();
    if (HASWS && tid < 64) {           // wave 0: total + overflow check
        uint32_t cc = (lane < NCH2) ? s_ccnt[lane] : 0u;
        int bad = (cc > SUBCAP) ? 1 : 0;
        int tot = (int)cc;
        #pragma unroll
        for (int d = 1; d < 64; d <<= 1) {
            tot += __shfl_down(tot, d);
            bad |= __shfl_down(bad, d);
        }
        if (lane == 0) { s_gc = tot; s_bad = bad; }
    }
    __syncthreads();
    if (dT) ts[2] = __builtin_amdgcn_s_memrealtime();

    const bool fast = HASWS && !s_bad && s_gc >= TOPK;   // ~always
    const int gc = HASWS ? s_gc : 0;

    uint64_t vc0 = 0, vc1 = 0;         // fast path: <=2 candidates per thread
    bool val0 = false, val1 = false;
    uint4 kv[KV4];                     // slow path: strided keys
    if (fast) {
        const uint64_t* gp = gcand + (size_t)task * NSLOT;
        {
            const int ch0 = tid / SUBCAP, i0 = tid - ch0 * SUBCAP;
            if (i0 < (int)s_ccnt[ch0]) { vc0 = gp[tid]; val0 = true; }
        }
        const int s1 = tid + NT;
        if (s1 < NSLOT) {
            const int ch1 = s1 / SUBCAP, i1 = s1 - ch1 * SUBCAP;
            if (i1 < (int)s_ccnt[ch1]) { vc1 = gp[s1]; val1 = true; }
        }
    } else {
        const float* sp = conf + (size_t)b * P_ * C_ + c;
        #pragma unroll
        for (int r = 0; r < KV4; ++r) {
            uint32_t uu[4];
            #pragma unroll
            for (int c4 = 0; c4 < 4; ++c4) {
                int p = (tid + r * NT) * 4 + c4;
                if (p < P_) {
                    float v = sp[(size_t)p * C_];
                    v = (v > CONF_T) ? v : -1.0f;
                    uu[c4] = f2s(v);
                } else uu[c4] = 0u;
            }
            kv[r] = make_uint4(uu[0], uu[1], uu[2], uu[3]);
        }
    }

    if (fast) {
        const uint32_t k0 = (uint32_t)(vc0 >> 32);
        const uint32_t k1 = (uint32_t)(vc1 >> 32);
        uint32_t vthr = T0;
        if (gc > 256) {
            uint32_t lo = T0, hi = 0xFFFFFFFFu;
            uint32_t t;
            {
                const float sc = s2f(T0);
                const float sn = 1.0f - (1.0f - sc) * (float)TGT / (float)gc;
                t = f2s(sn);
                if (!(t > lo && t < hi)) t = lo + ((hi - lo) >> 1);
            }
            for (int it = 0; ; ++it) {
                const int slot = it % 3;
                int my = (val0 && k0 >= t) + (val1 && k1 >= t);
                #pragma unroll
                for (int d = 1; d < 64; d <<= 1) my += __shfl_down(my, d);
                if (lane == 0) atomicAdd(&s_c3[slot], my);
                if (tid == 0) s_c3[(it + 1) % 3] = 0;
                __syncthreads();
                const int cnt = s_c3[slot];
                if (cnt >= TOPK && cnt <= 256) { vthr = t; break; }
                if (cnt > 256) lo = t; else hi = t;
                if (hi - lo <= 1) { vthr = lo; break; }
                uint32_t tn = 0;
                bool bis = (it >= 8) || (cnt == 0);
                if (!bis) {
                    const float sc = s2f(t);
                    const float sn = 1.0f - (1.0f - sc) * (float)TGT / (float)cnt;
                    tn = f2s(sn);
                    if (!(tn > lo && tn < hi)) bis = true;
                }
                if (bis) tn = lo + ((hi - lo) >> 1);
                t = tn;
            }
        }
        const bool p0v = val0 && k0 >= vthr;
        const bool p1v = val1 && k1 >= vthr;
        const unsigned long long mm0 = __ballot(p0v);
        const unsigned long long mm1 = __ballot(p1v);
        const int wtot = __popcll(mm0) + __popcll(mm1);
        int base = 0;
        if (lane == 0 && wtot) base = atomicAdd(&s_cnt, wtot);
        base = __shfl(base, 0);
        const unsigned long long below = (1ull << lane) - 1ull;
        const int o0 = base + __popcll(mm0 & below);
        const int o1 = base + __popcll(mm0) + __popcll(mm1 & below);
        if (p0v && o0 < 256) cand[o0] = vc0;
        if (p1v && o1 < 256) cand[o1] = vc1;
    } else {
        uint32_t lo = 0u, hi = 0xFFFFFFFFu;
        uint32_t t = f2s(1.0f - (float)TGT / (float)P_);
        uint32_t vthr = 0u;
        for (int it = 0; ; ++it) {
            const int slot = it & 1;
            int my = 0;
            #pragma unroll
            for (int r = 0; r < KV4; ++r)
                my += (kv[r].x >= t) + (kv[r].y >= t) + (kv[r].z >= t) + (kv[r].w >= t);
            #pragma unroll
            for (int d = 1; d < 64; d <<= 1) my += __shfl_down(my, d);
            if (lane == 0) atomicAdd(&s_c2[slot], my);
            __syncthreads();
            const int cnt = s_c2[slot];
            __syncthreads();
            if (tid == 0) s_c2[slot] = 0;
            if (cnt >= TOPK && cnt <= 256) { vthr = t; break; }
            if (cnt > 256) lo = t; else hi = t;
            if (hi - lo <= 1) { vthr = lo; break; }
            uint32_t tn = 0;
            bool bis = (it >= 8) || (cnt == 0);
            if (!bis) {
                const float sc = s2f(t);
                const float sn = 1.0f - (1.0f - sc) * (float)TGT / (float)cnt;
                tn = f2s(sn);
                if (!(tn > lo && tn < hi)) bis = true;
            }
            if (bis) tn = lo + ((hi - lo) >> 1);
            t = tn;
        }
        #pragma unroll
        for (int r = 0; r < KV4; ++r) {
            const int pb = (tid + r * NT) * 4;
            uint32_t uu[4] = {kv[r].x, kv[r].y, kv[r].z, kv[r].w};
            #pragma unroll
            for (int c4 = 0; c4 < 4; ++c4) {
                uint32_t u = uu[c4];
                if (u >= vthr) {
                    int pos = atomicAdd(&s_cnt, 1);
                    if (pos < 256) cand[pos] = ((uint64_t)u << 32) | (uint32_t)(~(uint32_t)(pb + c4));
                }
            }
        }
    }
    __syncthreads();
    if (dT) ts[3] = __builtin_amdgcn_s_memrealtime();
    if (tid < 256 && tid >= s_cnt) cand[tid] = 0ull;   // pad sorts to the end
    __syncthreads();

    // ---- bitonic sort 256 keys desc (val desc, idx asc) == jax.lax.top_k ----
    uint64_t v = (tid < 256) ? cand[tid] : 0ull;
    for (int kk = 2; kk <= 256; kk <<= 1) {
        for (int j = kk >> 1; j > 0; j >>= 1) {
            if (j >= 64) {
                __syncthreads();
                if (tid < 256) cand[tid] = v;
                __syncthreads();
                if (tid < 256) {
                    uint64_t pv = cand[tid ^ j];
                    bool keepmax = (((tid & j) == 0) == ((tid & kk) == 0));
                    v = keepmax ? (v > pv ? v : pv) : (v < pv ? v : pv);
                }
            } else if (tid < 256) {
                uint64_t pv = __shfl_xor(v, j);
                bool keepmax = (((tid & j) == 0) == ((tid & kk) == 0));
                v = keepmax ? (v > pv ? v : pv) : (v < pv ? v : pv);
            }
        }
    }
    if (dT) ts[4] = __builtin_amdgcn_s_memrealtime();

    // ---- decode top-200 boxes (exact ref f32 op order, no contraction) ----
    float my_sc = -1.0f;
    if (tid < TOPK) {
        uint32_t su = (uint32_t)(v >> 32);
        int p = (int)(~(uint32_t)v);
        my_sc = s2f(su);
        const float4 l4 = *(const float4*)(loc + ((size_t)b * P_ + p) * 4);
        const float4 pr = *(const float4*)(prior + (size_t)p * 4);
        float cx = __fadd_rn(pr.x, __fmul_rn(__fmul_rn(l4.x, 0.1f), pr.z));
        float cy = __fadd_rn(pr.y, __fmul_rn(__fmul_rn(l4.y, 0.1f), pr.w));
        float ew = (float)exp((double)__fmul_rn(l4.z, 0.2f));
        float eh = (float)exp((double)__fmul_rn(l4.w, 0.2f));
        float w  = __fmul_rn(pr.z, ew);
        float h  = __fmul_rn(pr.w, eh);
        float x1 = __fsub_rn(cx, __fmul_rn(w, 0.5f));
        float y1 = __fsub_rn(cy, __fmul_rn(h, 0.5f));
        float x2 = __fadd_rn(x1, w);
        float y2 = __fadd_rn(y1, h);
        bs[tid] = my_sc;
        bbox[tid] = make_float4(x1, y1, x2, y2);
        sar[tid] = __fmul_rn(__fsub_rn(x2, x1), __fsub_rn(y2, y1));  // exact ref area
    }
    {
        unsigned long long bm = __ballot(tid < TOPK && my_sc > CONF_T);
        if (lane == 0 && tid < 256) vmask[tid >> 6] = bm;
    }
    __syncthreads();
    if (dT) ts[5] = __builtin_amdgcn_s_memrealtime();

    // ---- pairwise IoU: balanced row-pairing; unroll-2 inner loop ----
    if (tid < 500) {
        const int rp = tid / 5;        // row-pair id in [0,100)
        const int s  = tid - rp * 5;   // sub-lane in [0,5)
        #pragma unroll
        for (int pass = 0; pass < 2; ++pass) {
            const int j  = pass ? (199 - rp) : rp;
            const int i0 = j + 1 + s;
            const float4 bj = bbox[j];
            const float  aj = sar[j];
            unsigned long long* mrow = &msk[j * 4];
            auto iou1 = [&](int i) {
                const float4 bi = bbox[i];
                float xx1 = fmaxf(bj.x, bi.x);
                float yy1 = fmaxf(bj.y, bi.y);
                float xx2 = fminf(bj.z, bi.z);
                float yy2 = fminf(bj.w, bi.w);
                float dx = fmaxf(__fsub_rn(xx2, xx1), 0.0f);
                float dy = fmaxf(__fsub_rn(yy2, yy1), 0.0f);
                float inter = __fmul_rn(dx, dy);
                if (inter > 0.0f) {
                    float ai = sar[i];
                    float uni = __fsub_rn(__fadd_rn(aj, ai), inter);
                    float t45 = __fmul_rn(NMS_T, uni);
                    float mar = __fmul_rn(t45, 1e-6f);
                    bool sup;
                    if (inter > __fadd_rn(t45, mar)) sup = true;
                    else if (inter < __fsub_rn(t45, mar)) sup = false;
                    else sup = (inter / uni > NMS_T);   // exact IEEE path, tie band only
                    if (sup) atomicOr(&mrow[i >> 6], 1ull << (i & 63));
                }
            };
            int i = i0;
            for (; i + 5 < TOPK; i += 10) { iou1(i); iou1(i + 5); }
            if (i < TOPK) iou1(i);
        }
    }
    __syncthreads();
    if (dT) ts[6] = __builtin_amdgcn_s_memrealtime();

    // ---- greedy NMS: word-blocked wave-0 scan ----
    if (tid < 64) {
        const int L = tid;
        auto or_reduce = [&](unsigned long long x) {
            #pragma unroll
            for (int d = 1; d < 64; d <<= 1) x |= __shfl_xor(x, d);
            return x;
        };
        unsigned long long s1 = 0, s2 = 0, s3 = 0;
        int nk = 0;
        #pragma unroll
        for (int w = 0; w < 4; ++w) {
            const int j = (w << 6) | L;
            unsigned long long r0 = 0, r1 = 0, r2 = 0, r3 = 0;
            if (j < TOPK) {
                const unsigned long long* mr = &msk[j * 4];
                r0 = mr[0]; r1 = mr[1]; r2 = mr[2]; r3 = mr[3];
            }
            const unsigned long long rself = (w == 0) ? r0 : (w == 1) ? r1
                                           : (w == 2) ? r2 : r3;
            unsigned long long sw = (w == 0) ? 0ull : (w == 1) ? s1
                                  : (w == 2) ? s2 : s3;
            unsigned long long alive = vmask[w] & ~sw;
            unsigned long long pm = 0;
            while (alive) {
                int jl = __ffsll(alive) - 1;
                if (L == 0) order[nk] = (w << 6) | jl;
                ++nk;
                sw |= __shfl(rself, jl);
                pm |= (1ull << jl);
                alive &= ~(sw | (1ull << jl));
            }
            if (pm) {
                const bool picked = (pm >> L) & 1ull;
                if (w == 0) {
                    s1 |= or_reduce(picked ? r1 : 0ull);
                    s2 |= or_reduce(picked ? r2 : 0ull);
                    s3 |= or_reduce(picked ? r3 : 0ull);
                } else if (w == 1) {
                    s2 |= or_reduce(picked ? r2 : 0ull);
                    s3 |= or_reduce(picked ? r3 : 0ull);
                } else if (w == 2) {
                    s3 |= or_reduce(picked ? r3 : 0ull);
                }
            }
        }
        if (L == 0) s_nk = nk;
    }
    __syncthreads();
    if (dT) ts[7] = __builtin_amdgcn_s_memrealtime();

    const int nk = s_nk;
    for (int e = tid; e < TOPK * 5; e += NT) {
        int r = e / 5;
        int f = e - r * 5;
        float val = 0.0f;
        if (r < nk) {
            int j = order[r];
            float4 bb = bbox[j];
            val = (f == 0) ? bs[j] : (f == 1) ? bb.x : (f == 2) ? bb.y
                : (f == 3) ? bb.z : bb.w;
        }
        outp[e] = val;
    }
    if (dT) {
        ts[8] = __builtin_amdgcn_s_memrealtime();
        unsigned long long* tp = tstamp + (size_t)task * 16;
        #pragma unroll
        for (int i = 0; i < 9; ++i) tp[i] = ts[i];
    }
}

// Publishes phase-K max latency (x SPIN_SCALE) as its own kernel duration.
// Workgroup_Size = 64*K fingerprints K in the profile.
__global__ void spin_kernel(const unsigned long long* __restrict__ tstamp, int k) {
    if (threadIdx.x == 0) {
        unsigned long long mx = 0;
        for (int t = 0; t < NTASK; ++t) {
            if (t % C_ == 0) continue;              // no stamps (poisoned memory)
            const unsigned long long* tp = tstamp + (size_t)t * 16;
            const unsigned long long a = tp[k - 1], b2 = tp[k];
            const unsigned long long m = (b2 > a) ? (b2 - a) : 0ull;
            if (m > mx) mx = m;
        }
        unsigned long long target = mx * SPIN_SCALE;
        if (target > SPIN_CAP) target = SPIN_CAP;   // garbage clamp
        const unsigned long long s0 = __builtin_amdgcn_s_memrealtime();
        while (__builtin_amdgcn_s_memrealtime() - s0 < target) {
            __builtin_amdgcn_s_sleep(2);
        }
    }
}

extern "C" void kernel_launch(void* const* d_in, const int* in_sizes, int n_in,
                              void* d_out, int out_size, void* d_ws, size_t ws_size,
                              hipStream_t stream) {
    const float* loc   = (const float*)d_in[0];
    const float* conf  = (const float*)d_in[1];
    const float* prior = (const float*)d_in[2];
    float* out = (float*)d_out;

    const size_t cnt_bytes  = (size_t)NTASK * NCH2 * sizeof(uint32_t);   // 94,080 (8-aligned)
    const size_t cand_bytes = (size_t)NTASK * NSLOT * sizeof(uint64_t);  // ~5.27 MB
    const size_t ts_bytes   = (size_t)NTASK * 16 * sizeof(unsigned long long); // 86 KB

    if (ws_size >= cnt_bytes + cand_bytes + ts_bytes) {
        uint32_t* gccnt = (uint32_t*)d_ws;
        uint64_t* gcand = (uint64_t*)((char*)d_ws + cnt_bytes);
        unsigned long long* tstamp =
            (unsigned long long*)((char*)d_ws + cnt_bytes + cand_bytes);
        scatter_cands<<<B_ * NCH2, 256, 0, stream>>>(conf, gccnt, gcand);
        detect_kernel<true><<<NTASK, NT, 0, stream>>>(loc, prior, gccnt, gcand, conf, out, tstamp);
        for (int k = 1; k <= 8; ++k)
            spin_kernel<<<1, 64 * k, 0, stream>>>(tstamp, k);
    } else if (ws_size >= cnt_bytes + cand_bytes) {
        uint32_t* gccnt = (uint32_t*)d_ws;
        uint64_t* gcand = (uint64_t*)((char*)d_ws + cnt_bytes);
        scatter_cands<<<B_ * NCH2, 256, 0, stream>>>(conf, gccnt, gcand);
        detect_kernel<true><<<NTASK, NT, 0, stream>>>(loc, prior, gccnt, gcand, conf, out, nullptr);
    } else {
        detect_kernel<false><<<NTASK, NT, 0, stream>>>(loc, prior, nullptr, nullptr, conf, out, nullptr);
    }
}

// Round 9
// 120.892 us; speedup vs baseline: 11.4773x; 11.4773x over previous
//
#include <hip/hip_runtime.h>
#include <stdint.h>

#define B_ 32
#define P_ 8732
#define C_ 21
#define TOPK 200
#define TGT 228        // count-search acceptance window center [200,256]
#define TGT0 300       // scatter pre-filter target count (mean; sigma~17)
#define SUBCAP 28      // per-(task,chunk) slot capacity; Poisson(8.8) P(>28)~1e-7
#define NCH2 35        // ceil(P_/256) chunks
#define NSLOT (NCH2 * SUBCAP)   // 980 slots/task
#define CONF_T 0.01f
#define NMS_T 0.45f
#define NT 512         // 8-wave blocks
#define KV4 5          // slow-path strided load: ceil((P_/4)/NT)
#define NTASK (B_ * C_)

__device__ __forceinline__ uint32_t f2s(float f) {
    uint32_t u = __float_as_uint(f);
    return (u & 0x80000000u) ? ~u : (u | 0x80000000u);
}
__device__ __forceinline__ float s2f(uint32_t s) {
    uint32_t b = (s & 0x80000000u) ? (s & 0x7FFFFFFFu) : ~s;
    return __uint_as_float(b);
}
__device__ __forceinline__ uint32_t keyof(float v) {
    return f2s((v > CONF_T) ? v : -1.0f);
}
__device__ __forceinline__ uint32_t thr0() {
    return f2s(1.0f - (float)TGT0 / (float)P_);   // folds to a constant
}

// conf (B,P,C) -> chunked per-task candidate lists, NO atomics anywhere.
__global__ __launch_bounds__(256) void scatter_cands(const float* __restrict__ conf,
                                                     uint32_t* __restrict__ gccnt,
                                                     uint64_t* __restrict__ gcand) {
    const int b = blockIdx.x / NCH2;
    const int ch = blockIdx.x % NCH2;
    const int p0 = ch * 256;
    const int n = min(256, P_ - p0);          // 256 or 28
    const int tid = threadIdx.x;
    const int lane = tid & 63;
    const int cs = tid >> 6;                  // wave id = class slice 0..3
    __shared__ float tile[256 * C_];
    const float4* src4 = (const float4*)(conf + ((size_t)b * P_ + p0) * C_);
    float4* tile4 = (float4*)tile;
    const int tot4 = (n * C_) >> 2;
    for (int i = tid; i < tot4; i += 256) tile4[i] = src4[i];
    __syncthreads();
    const uint32_t T0 = thr0();
    for (int c = (cs == 0 ? 4 : cs); c < C_; c += 4) {   // class 0 output is zeroed: skip
        uint32_t kk[4];
        #pragma unroll
        for (int k = 0; k < 4; ++k) {
            const int r = lane + 64 * k;
            if (r < n) kk[k] = keyof(tile[r * C_ + c]);
            else       kk[k] = 0u;            // 0 < T0 (T0 has top bit set)
        }
        const unsigned long long m0 = __ballot(kk[0] >= T0);
        const unsigned long long m1 = __ballot(kk[1] >= T0);
        const unsigned long long m2 = __ballot(kk[2] >= T0);
        const unsigned long long m3 = __ballot(kk[3] >= T0);
        const int c0 = __popcll(m0), c1 = __popcll(m1), c2 = __popcll(m2), c3 = __popcll(m3);
        const int total = c0 + c1 + c2 + c3;
        const int task = b * C_ + c;
        uint64_t* dst = gcand + ((size_t)task * NCH2 + ch) * SUBCAP;
        {
            const unsigned long long below = (1ull << lane) - 1ull;
            const int cum[4] = {0, c0, c0 + c1, c0 + c1 + c2};
            const unsigned long long mm[4] = {m0, m1, m2, m3};
            #pragma unroll
            for (int k = 0; k < 4; ++k) {
                if (kk[k] >= T0) {
                    const int pos = cum[k] + __popcll(mm[k] & below);
                    if (pos < SUBCAP) {
                        const int p = p0 + lane + 64 * k;
                        dst[pos] = ((uint64_t)kk[k] << 32) | (uint32_t)(~(uint32_t)p);
                    }
                }
            }
        }
        if (lane == 0) gccnt[(size_t)task * NCH2 + ch] = (uint32_t)total;
    }
}

// Production detect = R3 kernel with one change (R8 spin-ladder evidence:
// IoU phase max wall = 35us of 48 -> divergent per-hit LDS atomicOr storm):
// IoU suppression bits now batch in a REGISTER per (pass,word) and commit
// with <=8 atomicOr/thread. Same bits; OR commutes; order-independent.
template<bool HASWS>
__global__ __launch_bounds__(NT, 6) void detect_kernel(
    const float* __restrict__ loc, const float* __restrict__ prior,
    const uint32_t* __restrict__ gccnt, const uint64_t* __restrict__ gcand,
    const float* __restrict__ conf, float* __restrict__ out)
{
    const int task = blockIdx.x;
    const int b = task / C_;
    const int c = task % C_;
    const int tid = threadIdx.x;
    const int lane = tid & 63;
    float* outp = out + (size_t)task * TOPK * 5;

    if (c == 0) {  // out.at[:,0].set(0.0)
        for (int e = tid; e < TOPK * 5; e += NT) outp[e] = 0.0f;
        return;
    }

    __shared__ uint64_t cand[256];
    __shared__ float4 bbox[TOPK];
    __shared__ float bs[TOPK];
    __shared__ float sar[TOPK];
    __shared__ unsigned long long msk[TOPK * 4];
    __shared__ unsigned long long vmask[4];
    __shared__ int order[TOPK];
    __shared__ int s_cnt, s_nk;
    __shared__ int s_c2[2];
    __shared__ int s_c3[3];            // 3-slot rotation: 1 barrier/search-iter
    __shared__ uint32_t s_ccnt[NCH2];
    __shared__ int s_gc, s_bad;

    const uint32_t T0 = thr0();

    if (tid == 0) s_cnt = 0;
    if (tid < 2) s_c2[tid] = 0;
    if (tid < 3) s_c3[tid] = 0;
    if (HASWS && tid < NCH2) s_ccnt[tid] = gccnt[(size_t)task * NCH2 + tid];
    for (int i2 = tid; i2 < TOPK * 4; i2 += NT) msk[i2] = 0ull;
    __syncthreads();
    if (HASWS && tid < 64) {           // wave 0: total + overflow check
        uint32_t cc = (lane < NCH2) ? s_ccnt[lane] : 0u;
        int bad = (cc > SUBCAP) ? 1 : 0;
        int tot = (int)cc;
        #pragma unroll
        for (int d = 1; d < 64; d <<= 1) {
            tot += __shfl_down(tot, d);
            bad |= __shfl_down(bad, d);
        }
        if (lane == 0) { s_gc = tot; s_bad = bad; }
    }
    __syncthreads();

    const bool fast = HASWS && !s_bad && s_gc >= TOPK;   // ~always
    const int gc = HASWS ? s_gc : 0;

    uint64_t vc0 = 0, vc1 = 0;         // fast path: <=2 candidates per thread
    bool val0 = false, val1 = false;
    uint4 kv[KV4];                     // slow path: strided keys
    if (fast) {
        const uint64_t* gp = gcand + (size_t)task * NSLOT;
        {
            const int ch0 = tid / SUBCAP, i0 = tid - ch0 * SUBCAP;
            if (i0 < (int)s_ccnt[ch0]) { vc0 = gp[tid]; val0 = true; }
        }
        const int s1 = tid + NT;
        if (s1 < NSLOT) {
            const int ch1 = s1 / SUBCAP, i1 = s1 - ch1 * SUBCAP;
            if (i1 < (int)s_ccnt[ch1]) { vc1 = gp[s1]; val1 = true; }
        }
    } else {
        const float* sp = conf + (size_t)b * P_ * C_ + c;
        #pragma unroll
        for (int r = 0; r < KV4; ++r) {
            uint32_t uu[4];
            #pragma unroll
            for (int c4 = 0; c4 < 4; ++c4) {
                int p = (tid + r * NT) * 4 + c4;
                if (p < P_) {
                    float v = sp[(size_t)p * C_];
                    v = (v > CONF_T) ? v : -1.0f;
                    uu[c4] = f2s(v);
                } else uu[c4] = 0u;
            }
            kv[r] = make_uint4(uu[0], uu[1], uu[2], uu[3]);
        }
    }

    if (fast) {
        const uint32_t k0 = (uint32_t)(vc0 >> 32);
        const uint32_t k1 = (uint32_t)(vc1 >> 32);
        uint32_t vthr = T0;
        if (gc > 256) {
            uint32_t lo = T0, hi = 0xFFFFFFFFu;
            uint32_t t;
            {
                const float sc = s2f(T0);
                const float sn = 1.0f - (1.0f - sc) * (float)TGT / (float)gc;
                t = f2s(sn);
                if (!(t > lo && t < hi)) t = lo + ((hi - lo) >> 1);
            }
            for (int it = 0; ; ++it) {
                const int slot = it % 3;
                int my = (val0 && k0 >= t) + (val1 && k1 >= t);
                #pragma unroll
                for (int d = 1; d < 64; d <<= 1) my += __shfl_down(my, d);
                if (lane == 0) atomicAdd(&s_c3[slot], my);
                if (tid == 0) s_c3[(it + 1) % 3] = 0;
                __syncthreads();
                const int cnt = s_c3[slot];
                if (cnt >= TOPK && cnt <= 256) { vthr = t; break; }
                if (cnt > 256) lo = t; else hi = t;
                if (hi - lo <= 1) { vthr = lo; break; }
                uint32_t tn = 0;
                bool bis = (it >= 8) || (cnt == 0);
                if (!bis) {
                    const float sc = s2f(t);
                    const float sn = 1.0f - (1.0f - sc) * (float)TGT / (float)cnt;
                    tn = f2s(sn);
                    if (!(tn > lo && tn < hi)) bis = true;
                }
                if (bis) tn = lo + ((hi - lo) >> 1);
                t = tn;
            }
        }
        const bool p0v = val0 && k0 >= vthr;
        const bool p1v = val1 && k1 >= vthr;
        const unsigned long long mm0 = __ballot(p0v);
        const unsigned long long mm1 = __ballot(p1v);
        const int wtot = __popcll(mm0) + __popcll(mm1);
        int base = 0;
        if (lane == 0 && wtot) base = atomicAdd(&s_cnt, wtot);
        base = __shfl(base, 0);
        const unsigned long long below = (1ull << lane) - 1ull;
        const int o0 = base + __popcll(mm0 & below);
        const int o1 = base + __popcll(mm0) + __popcll(mm1 & below);
        if (p0v && o0 < 256) cand[o0] = vc0;
        if (p1v && o1 < 256) cand[o1] = vc1;
    } else {
        uint32_t lo = 0u, hi = 0xFFFFFFFFu;
        uint32_t t = f2s(1.0f - (float)TGT / (float)P_);
        uint32_t vthr = 0u;
        for (int it = 0; ; ++it) {
            const int slot = it & 1;
            int my = 0;
            #pragma unroll
            for (int r = 0; r < KV4; ++r)
                my += (kv[r].x >= t) + (kv[r].y >= t) + (kv[r].z >= t) + (kv[r].w >= t);
            #pragma unroll
            for (int d = 1; d < 64; d <<= 1) my += __shfl_down(my, d);
            if (lane == 0) atomicAdd(&s_c2[slot], my);
            __syncthreads();
            const int cnt = s_c2[slot];
            __syncthreads();
            if (tid == 0) s_c2[slot] = 0;
            if (cnt >= TOPK && cnt <= 256) { vthr = t; break; }
            if (cnt > 256) lo = t; else hi = t;
            if (hi - lo <= 1) { vthr = lo; break; }
            uint32_t tn = 0;
            bool bis = (it >= 8) || (cnt == 0);
            if (!bis) {
                const float sc = s2f(t);
                const float sn = 1.0f - (1.0f - sc) * (float)TGT / (float)cnt;
                tn = f2s(sn);
                if (!(tn > lo && tn < hi)) bis = true;
            }
            if (bis) tn = lo + ((hi - lo) >> 1);
            t = tn;
        }
        #pragma unroll
        for (int r = 0; r < KV4; ++r) {
            const int pb = (tid + r * NT) * 4;
            uint32_t uu[4] = {kv[r].x, kv[r].y, kv[r].z, kv[r].w};
            #pragma unroll
            for (int c4 = 0; c4 < 4; ++c4) {
                uint32_t u = uu[c4];
                if (u >= vthr) {
                    int pos = atomicAdd(&s_cnt, 1);
                    if (pos < 256) cand[pos] = ((uint64_t)u << 32) | (uint32_t)(~(uint32_t)(pb + c4));
                }
            }
        }
    }
    __syncthreads();
    if (tid < 256 && tid >= s_cnt) cand[tid] = 0ull;   // pad sorts to the end
    __syncthreads();

    // ---- bitonic sort 256 keys desc (val desc, idx asc) == jax.lax.top_k ----
    uint64_t v = (tid < 256) ? cand[tid] : 0ull;
    for (int kk = 2; kk <= 256; kk <<= 1) {
        for (int j = kk >> 1; j > 0; j >>= 1) {
            if (j >= 64) {
                __syncthreads();
                if (tid < 256) cand[tid] = v;
                __syncthreads();
                if (tid < 256) {
                    uint64_t pv = cand[tid ^ j];
                    bool keepmax = (((tid & j) == 0) == ((tid & kk) == 0));
                    v = keepmax ? (v > pv ? v : pv) : (v < pv ? v : pv);
                }
            } else if (tid < 256) {
                uint64_t pv = __shfl_xor(v, j);
                bool keepmax = (((tid & j) == 0) == ((tid & kk) == 0));
                v = keepmax ? (v > pv ? v : pv) : (v < pv ? v : pv);
            }
        }
    }

    // ---- decode top-200 boxes (exact ref f32 op order, no contraction) ----
    float my_sc = -1.0f;
    if (tid < TOPK) {
        uint32_t su = (uint32_t)(v >> 32);
        int p = (int)(~(uint32_t)v);
        my_sc = s2f(su);
        const float4 l4 = *(const float4*)(loc + ((size_t)b * P_ + p) * 4);
        const float4 pr = *(const float4*)(prior + (size_t)p * 4);
        float cx = __fadd_rn(pr.x, __fmul_rn(__fmul_rn(l4.x, 0.1f), pr.z));
        float cy = __fadd_rn(pr.y, __fmul_rn(__fmul_rn(l4.y, 0.1f), pr.w));
        float ew = (float)exp((double)__fmul_rn(l4.z, 0.2f));
        float eh = (float)exp((double)__fmul_rn(l4.w, 0.2f));
        float w  = __fmul_rn(pr.z, ew);
        float h  = __fmul_rn(pr.w, eh);
        float x1 = __fsub_rn(cx, __fmul_rn(w, 0.5f));
        float y1 = __fsub_rn(cy, __fmul_rn(h, 0.5f));
        float x2 = __fadd_rn(x1, w);
        float y2 = __fadd_rn(y1, h);
        bs[tid] = my_sc;
        bbox[tid] = make_float4(x1, y1, x2, y2);
        sar[tid] = __fmul_rn(__fsub_rn(x2, x1), __fsub_rn(y2, y1));  // exact ref area
    }
    {
        unsigned long long bm = __ballot(tid < TOPK && my_sc > CONF_T);
        if (lane == 0 && tid < 256) vmask[tid >> 6] = bm;
    }
    __syncthreads();

    // ---- pairwise IoU: register-batched suppression bits ----
    // Per (pass, word w): accumulate hits into register lw (static index),
    // commit once per non-empty word. <=8 atomicOr/thread vs ~40 divergent.
    if (tid < 500) {
        const int rp = tid / 5;        // row-pair id in [0,100)
        const int s  = tid - rp * 5;   // sub-lane in [0,5)
        #pragma unroll
        for (int pass = 0; pass < 2; ++pass) {
            const int j  = pass ? (199 - rp) : rp;
            const int i0 = j + 1 + s;
            const float4 bj = bbox[j];
            const float  aj = sar[j];
            unsigned long long* mrow = &msk[j * 4];
            #pragma unroll
            for (int w = 0; w < 4; ++w) {
                const int wlo = w << 6;
                const int whi = (wlo + 64 < TOPK) ? wlo + 64 : TOPK;
                int i = i0;
                if (i < wlo) i += ((wlo - i + 4) / 5) * 5;   // first i>=wlo, i==i0 mod 5
                unsigned long long lw = 0ull;
                for (; i < whi; i += 5) {
                    const float4 bi = bbox[i];
                    float xx1 = fmaxf(bj.x, bi.x);
                    float yy1 = fmaxf(bj.y, bi.y);
                    float xx2 = fminf(bj.z, bi.z);
                    float yy2 = fminf(bj.w, bi.w);
                    float dx = fmaxf(__fsub_rn(xx2, xx1), 0.0f);
                    float dy = fmaxf(__fsub_rn(yy2, yy1), 0.0f);
                    float inter = __fmul_rn(dx, dy);
                    bool sup = false;
                    if (inter > 0.0f) {
                        float ai = sar[i];
                        float uni = __fsub_rn(__fadd_rn(aj, ai), inter);
                        float t45 = __fmul_rn(NMS_T, uni);
                        float mar = __fmul_rn(t45, 1e-6f);
                        sup = inter > __fadd_rn(t45, mar);
                        if (!sup && !(inter < __fsub_rn(t45, mar))) {
                            sup = (inter / uni > NMS_T);   // exact IEEE, tie band only
                        }
                    }
                    if (sup) lw |= 1ull << (i & 63);
                }
                if (lw) atomicOr(&mrow[w], lw);
            }
        }
    }
    __syncthreads();

    // ---- greedy NMS: word-blocked wave-0 scan ----
    if (tid < 64) {
        const int L = tid;
        auto or_reduce = [&](unsigned long long x) {
            #pragma unroll
            for (int d = 1; d < 64; d <<= 1) x |= __shfl_xor(x, d);
            return x;
        };
        unsigned long long s1 = 0, s2 = 0, s3 = 0;
        int nk = 0;
        #pragma unroll
        for (int w = 0; w < 4; ++w) {
            const int j = (w << 6) | L;
            unsigned long long r0 = 0, r1 = 0, r2 = 0, r3 = 0;
            if (j < TOPK) {
                const unsigned long long* mr = &msk[j * 4];
                r0 = mr[0]; r1 = mr[1]; r2 = mr[2]; r3 = mr[3];
            }
            const unsigned long long rself = (w == 0) ? r0 : (w == 1) ? r1
                                           : (w == 2) ? r2 : r3;
            unsigned long long sw = (w == 0) ? 0ull : (w == 1) ? s1
                                  : (w == 2) ? s2 : s3;
            unsigned long long alive = vmask[w] & ~sw;
            unsigned long long pm = 0;
            while (alive) {
                int jl = __ffsll(alive) - 1;
                if (L == 0) order[nk] = (w << 6) | jl;
                ++nk;
                sw |= __shfl(rself, jl);
                pm |= (1ull << jl);
                alive &= ~(sw | (1ull << jl));
            }
            if (pm) {
                const bool picked = (pm >> L) & 1ull;
                if (w == 0) {
                    s1 |= or_reduce(picked ? r1 : 0ull);
                    s2 |= or_reduce(picked ? r2 : 0ull);
                    s3 |= or_reduce(picked ? r3 : 0ull);
                } else if (w == 1) {
                    s2 |= or_reduce(picked ? r2 : 0ull);
                    s3 |= or_reduce(picked ? r3 : 0ull);
                } else if (w == 2) {
                    s3 |= or_reduce(picked ? r3 : 0ull);
                }
            }
        }
        if (L == 0) s_nk = nk;
    }
    __syncthreads();

    const int nk = s_nk;
    for (int e = tid; e < TOPK * 5; e += NT) {
        int r = e / 5;
        int f = e - r * 5;
        float val = 0.0f;
        if (r < nk) {
            int j = order[r];
            float4 bb = bbox[j];
            val = (f == 0) ? bs[j] : (f == 1) ? bb.x : (f == 2) ? bb.y
                : (f == 3) ? bb.z : bb.w;
        }
        outp[e] = val;
    }
}

extern "C" void kernel_launch(void* const* d_in, const int* in_sizes, int n_in,
                              void* d_out, int out_size, void* d_ws, size_t ws_size,
                              hipStream_t stream) {
    const float* loc   = (const float*)d_in[0];
    const float* conf  = (const float*)d_in[1];
    const float* prior = (const float*)d_in[2];
    float* out = (float*)d_out;

    const size_t cnt_bytes  = (size_t)NTASK * NCH2 * sizeof(uint32_t);   // 94,080 (8-aligned)
    const size_t cand_bytes = (size_t)NTASK * NSLOT * sizeof(uint64_t);  // ~5.27 MB
    if (ws_size >= cnt_bytes + cand_bytes) {
        uint32_t* gccnt = (uint32_t*)d_ws;
        uint64_t* gcand = (uint64_t*)((char*)d_ws + cnt_bytes);
        scatter_cands<<<B_ * NCH2, 256, 0, stream>>>(conf, gccnt, gcand);
        detect_kernel<true><<<NTASK, NT, 0, stream>>>(loc, prior, gccnt, gcand, conf, out);
    } else {
        detect_kernel<false><<<NTASK, NT, 0, stream>>>(loc, prior, nullptr, nullptr, conf, out);
    }
}